// Round 5
// baseline (111.323 us; speedup 1.0000x reference)
//
#include <hip/hip_runtime.h>
#include <math.h>

// Problem constants (from reference setup_inputs)
#define NQ 2048
#define NB 8192
#define DIM 32

#define LOG2E 1.44269504088896340736f

typedef _Float16 half8 __attribute__((ext_vector_type(8)));
typedef float    f32x4 __attribute__((ext_vector_type(4)));

// ---------------- workspace layout (bytes, 64-B aligned) ----------------
#define WS_ACC 0         // 2*NQ f32 (16384 B)
#define WS_Q2  16448     // NQ f32
#define WS_B2  24640     // NB f32
#define WS_XQH 57408     // NQ*DIM f16   (xq*w rounded)
#define WS_XBH 188480    // NB*DIM f16   (-2*(xb*w) rounded-then-scaled)

// Pre: convert rows to f16 with norms computed FROM THE ROUNDED VALUES
// (so mfma d2 = ||a-b||^2 has no representation-mismatch cancellation).
// XBh is stored pre-scaled by -2 (exact: exponent+1 + sign) so the main
// MFMA with C = q2+b2 emits d2 directly.
__global__ __launch_bounds__(256) void relnw_pre(
    const float* __restrict__ xq, const float* __restrict__ xb,
    const float* __restrict__ w,
    _Float16* __restrict__ XQh, _Float16* __restrict__ XBh,
    float* __restrict__ q2, float* __restrict__ b2,
    float* __restrict__ acc)
{
    const int tid = threadIdx.x;
    const int gi  = blockIdx.x * 256 + tid;
    if (gi < 2 * NQ) acc[gi] = 0.f;      // zero atomic accumulators

    const int row = blockIdx.x * 64 + (tid >> 2);
    const int p   = tid & 3;             // 8-elem chunk within the row
    if (row >= NQ + NB) return;

    const float* src; _Float16* dst; float* s2; float scale;
    if (row < NQ) { src = xq + (size_t)row * DIM;
                    dst = XQh + (size_t)row * DIM; s2 = q2 + row; scale = 1.f; }
    else          { int j = row - NQ;
                    src = xb + (size_t)j * DIM;
                    dst = XBh + (size_t)j * DIM;   s2 = b2 + j;   scale = -2.f; }

    const float4 xa  = ((const float4*)src)[p * 2];
    const float4 xbv = ((const float4*)src)[p * 2 + 1];
    const float4 wa  = ((const float4*)w)[p * 2];
    const float4 wb  = ((const float4*)w)[p * 2 + 1];
    const float xs[8]  = {xa.x, xa.y, xa.z, xa.w, xbv.x, xbv.y, xbv.z, xbv.w};
    const float ws_[8] = {wa.x, wa.y, wa.z, wa.w, wb.x, wb.y, wb.z, wb.w};

    half8 h;
    float s = 0.f;
#pragma unroll
    for (int c = 0; c < 8; ++c) {
        float t = xs[c] * ws_[c];
        _Float16 hh = (_Float16)t;       // the rounding
        float th = (float)hh;
        s = fmaf(th, th, s);             // norm of the ROUNDED vector
        h[c] = (_Float16)(th * scale);   // exact scaling
    }
    *(half8*)(dst + p * 8) = h;          // coalesced 16-B store

    // row-norm: reduce over the 4 chunk-lanes (low 2 lane bits)
    s += __shfl_xor(s, 1, 64);
    s += __shfl_xor(s, 2, 64);
    if (p == 0) *s2 = s;
}

// Main: grid (8, 128) = 1024 blocks (4/CU resident), 256 threads (4 waves).
// Wave task: one 16-query tile x 256-bg chunk = 16 MFMA tiles (4 quarters).
//
// R10 (keep): r staged via global_load_lds in contiguous bursts; swizzle
// byte^=((row&7)<<4) pre-applied on the GLOBAL source (gl_lds dest must be
// linear — both-sides-or-neither), read side applies the same XOR.
//
// R11: R4 paid full memory latency TWICE serially (vmcnt(0) drain after
// each 8-KB stage; zero stage/compute overlap; main ~18.5us vs 10.6 floor).
// Now: 4 quarters of 4 KB (16 rows x 256 B), double-buffered in the same
// 8 KB/wave, counted vmcnt (T3/T4): vmcnt(4)->compute Q0 while Q1 flies;
// issue afC/afD+Q2, vmcnt(12)->compute Q1; issue Q3, vmcnt(4)->compute Q2;
// vmcnt(0)->compute Q3. Queue never drains until the end; >=4KB/wave in
// flight keeps HBM continuously fed. sched_barrier(0) pins every issue
// batch and every wait (else compiler sinks a batch past its counted wait
// and the count breaks — rule #18). Counts verified against issue order:
// [afA,afB(8) aux(2) Q0(4) Q1(4)] vm4; [afC,afD(8) Q2(4)] vm12; [Q3(4)]
// vm4; vm0. WAR on LDS is safe: a quarter's buffer is re-staged only after
// its ds_reads' data was consumed (program order), and gl_lds writes land
// at data-return, after issue.
// LDS 40960 B/block -> 4 blocks/CU, 16 waves/CU kept. Math identical.
//
// R8 lesson (keep): __launch_bounds__(256,2) — (256,4) caps VGPR at 64 and
// spills everything. R5 lesson (keep): no __threadfence / fused finalize.
#define BT_PER_WAVE 16
#define BG_PER_WAVE (BT_PER_WAVE * 16)   // 256

#define GLDS(GSRC, LDST)                                                    \
  __builtin_amdgcn_global_load_lds(                                         \
      (const __attribute__((address_space(1))) void*)(GSRC),                \
      (__attribute__((address_space(3))) void*)(LDST), 16, 0, 0)

#define SBAR __builtin_amdgcn_sched_barrier(0)

// compute one 4-KB quarter (4 MFMA tiles) out of LDS buffer BUF
#define COMPQ(BUF, QTR, AF)                                                 \
  { _Pragma("unroll") for (int it = 0; it < 4; ++it) {                      \
      const int co = (QTR) * 64 + it * 16 + quad * 4;                       \
      const f32x4 bb = *(const f32x4*)(b2l + co);                           \
      const f32x4 yv = *(const f32x4*)(ybl + co);                           \
      const f32x4 rr = *(const f32x4*)((BUF) + m * 256 +                    \
                           ((it * 64 + quad * 16) ^ swz));                  \
      f32x4 cin;                                                            \
      _Pragma("unroll") for (int g = 0; g < 4; ++g) cin[g] = q2s + bb[g];   \
      const f32x4 d2v = __builtin_amdgcn_mfma_f32_16x16x32_f16(             \
          AF[it], qfrag, cin, 0, 0, 0);                                     \
      _Pragma("unroll") for (int g = 0; g < 4; ++g) {                       \
        float d2   = fmaxf(d2v[g], 0.f);                                    \
        float dist = __builtin_amdgcn_sqrtf(d2);                            \
        float e    = fmaf(dist, c1, rr[g] * c2);                            \
        float k    = __builtin_amdgcn_exp2f(e);                             \
        sk += k;                                                            \
        sky = fmaf(k, yv[g], sky); } } }

__global__ __launch_bounds__(256, 2) void relnw_main(
    const _Float16* __restrict__ XQh,  // (NQ, DIM)
    const _Float16* __restrict__ XBh,  // (NB, DIM), pre-scaled by -2
    const float* __restrict__ q2,      // (NQ,)
    const float* __restrict__ b2,      // (NB,)
    const float* __restrict__ yb,      // (NB,)
    const float* __restrict__ r,       // (NQ, NB)
    const float* __restrict__ sigma,   // (1,)
    const float* __restrict__ rscale,  // (1,)
    float* __restrict__ acc)           // [0:NQ]=sum_k, [NQ:2NQ]=sum_k*y
{
    // LDS: per wave 2x4KB r quarter buffers; per block +4x1KB b2, +4x1KB yb
    __shared__ char lds[4 * 8192 + 4 * 1024 + 4 * 1024];  // 40960 B

    const int tid  = threadIdx.x;
    const int lane = tid & 63;
    const int wid  = tid >> 6;
    const int m    = lane & 15;   // query col (D) / A-row feeder
    const int quad = lane >> 4;   // 0..3

    const int q0     = blockIdx.y * 16;
    const int bstart = (blockIdx.x * 4 + wid) * BG_PER_WAVE;

    char*  bufA = lds + wid * 8192;
    char*  bufB = bufA + 4096;
    float* b2l  = (float*)(lds + 32768 + wid * 1024);
    float* ybl  = (float*)(lds + 36864 + wid * 1024);

    const float c1 = -LOG2E / sigma[0];   // coeff on dist (log2 space)
    const float c2 =  LOG2E * rscale[0];  // coeff on r

    // B operand: this wave's 16 queries (fixed across the bg loop)
    const half8 qfrag = *(const half8*)(XQh + (size_t)(q0 + m) * DIM + quad * 8);
    const float q2s   = q2[q0 + m];
    const int   swz   = (m & 7) << 4;

    // r stage source: instr j covers rows 4j+(lane>>4), 256 B contiguous per
    // 16-lane group; XOR pre-applies the LDS read swizzle (within segment).
    const int g16 = lane >> 4;
    const int l16 = lane & 15;
    const char* rsrc[4];
#pragma unroll
    for (int j = 0; j < 4; ++j) {
        const int rw = 4 * j + g16;
        rsrc[j] = (const char*)(r + (size_t)(q0 + rw) * NB + bstart)
                  + ((l16 * 16) ^ ((rw & 7) << 4));
    }

#define AFRAG(I) (*(const half8*)(XBh + \
        (size_t)(bstart + (I) * 16 + m) * DIM + quad * 8))

    half8 afA[4], afB[4], afC[4], afD[4];
    float sk = 0.f, sky = 0.f;

    // ---- prologue issues: afA,afB (8) | aux (2) | Q0->A (4) | Q1->B (4) ----
#pragma unroll
    for (int i = 0; i < 4; ++i) afA[i] = AFRAG(i);
#pragma unroll
    for (int i = 0; i < 4; ++i) afB[i] = AFRAG(4 + i);
    GLDS((const char*)(b2 + bstart) + lane * 16, b2l);
    GLDS((const char*)(yb + bstart) + lane * 16, ybl);
#pragma unroll
    for (int j = 0; j < 4; ++j) GLDS(rsrc[j],       bufA + j * 1024);
#pragma unroll
    for (int j = 0; j < 4; ++j) GLDS(rsrc[j] + 256, bufB + j * 1024);
    SBAR;
    asm volatile("s_waitcnt vmcnt(4)" ::: "memory");  // afA,afB,aux,Q0 done
    SBAR;

    COMPQ(bufA, 0, afA)

    // ---- issue afC,afD (8) | Q2->A (4); outstanding = Q1(4)+12 = 16 ----
#pragma unroll
    for (int i = 0; i < 4; ++i) afC[i] = AFRAG(8 + i);
#pragma unroll
    for (int i = 0; i < 4; ++i) afD[i] = AFRAG(12 + i);
#pragma unroll
    for (int j = 0; j < 4; ++j) GLDS(rsrc[j] + 512, bufA + j * 1024);
    SBAR;
    asm volatile("s_waitcnt vmcnt(12)" ::: "memory"); // Q1 done
    SBAR;

    COMPQ(bufB, 1, afB)

    // ---- issue Q3->B (4); outstanding = afC,afD(8)+Q2(4)+Q3(4) = 16 ----
#pragma unroll
    for (int j = 0; j < 4; ++j) GLDS(rsrc[j] + 768, bufB + j * 1024);
    SBAR;
    asm volatile("s_waitcnt vmcnt(4)" ::: "memory");  // afC,afD,Q2 done
    SBAR;

    COMPQ(bufA, 2, afC)

    asm volatile("s_waitcnt vmcnt(0)" ::: "memory");  // Q3 done
    SBAR;

    COMPQ(bufB, 3, afD)

    // All 4 values of a lane belong to query q0+m; reduce across quads.
    sk  += __shfl_xor(sk, 16, 64);
    sk  += __shfl_xor(sk, 32, 64);
    sky += __shfl_xor(sky, 16, 64);
    sky += __shfl_xor(sky, 32, 64);
    if (lane < 16) {
        atomicAdd(acc + (q0 + m),      sk);
        atomicAdd(acc + NQ + (q0 + m), sky);
    }
}

__global__ __launch_bounds__(256) void relnw_finalize(
    const float* __restrict__ acc, float* __restrict__ out)
{
    int q = blockIdx.x * 256 + threadIdx.x;
    if (q < NQ)
        out[q] = acc[NQ + q] / (acc[q] + 1e-8f);
}

extern "C" void kernel_launch(void* const* d_in, const int* in_sizes, int n_in,
                              void* d_out, int out_size, void* d_ws, size_t ws_size,
                              hipStream_t stream) {
    const float* xb     = (const float*)d_in[0]; // (8192,32)
    const float* yb     = (const float*)d_in[1]; // (8192,)
    const float* xq     = (const float*)d_in[2]; // (2048,32)
    const float* r      = (const float*)d_in[3]; // (2048,8192)
    const float* sigma  = (const float*)d_in[4]; // (1,)
    const float* rscale = (const float*)d_in[5]; // (1,)
    const float* w      = (const float*)d_in[6]; // (32,)
    float* out = (float*)d_out;

    char* ws = (char*)d_ws;
    float*    acc = (float*)(ws + WS_ACC);
    float*    q2  = (float*)(ws + WS_Q2);
    float*    b2  = (float*)(ws + WS_B2);
    _Float16* XQh = (_Float16*)(ws + WS_XQH);
    _Float16* XBh = (_Float16*)(ws + WS_XBH);

    relnw_pre<<<(NQ + NB) / 64, 256, 0, stream>>>(xq, xb, w, XQh, XBh, q2, b2, acc);

    dim3 grid(NB / (4 * BG_PER_WAVE), NQ / 16);  // (8, 128) = 1024 blocks
    relnw_main<<<grid, 256, 0, stream>>>(XQh, XBh, q2, b2, yb, r, sigma, rscale, acc);

    relnw_finalize<<<(NQ + 255) / 256, 256, 0, stream>>>(acc, out);
}

// Round 6
// 110.002 us; speedup vs baseline: 1.0120x; 1.0120x over previous
//
#include <hip/hip_runtime.h>
#include <math.h>

// Problem constants (from reference setup_inputs)
#define NQ 2048
#define NB 8192
#define DIM 32

#define LOG2E 1.44269504088896340736f

typedef _Float16 half8 __attribute__((ext_vector_type(8)));
typedef float    f32x4 __attribute__((ext_vector_type(4)));

// ---------------- workspace layout (bytes, 64-B aligned) ----------------
#define WS_ACC 0         // 2*NQ f32 (16384 B)
#define WS_Q2  16448     // NQ f32
#define WS_B2  24640     // NB f32
#define WS_XQH 57408     // NQ*DIM f16   (xq*w rounded)
#define WS_XBH 188480    // NB*DIM f16   (-2*(xb*w) rounded-then-scaled)

// Pre: convert rows to f16 with norms computed FROM THE ROUNDED VALUES
// (so mfma d2 = ||a-b||^2 has no representation-mismatch cancellation).
// XBh is stored pre-scaled by -2 (exact: exponent+1 + sign) so the main
// MFMA with C = q2+b2 emits d2 directly.
__global__ __launch_bounds__(256) void relnw_pre(
    const float* __restrict__ xq, const float* __restrict__ xb,
    const float* __restrict__ w,
    _Float16* __restrict__ XQh, _Float16* __restrict__ XBh,
    float* __restrict__ q2, float* __restrict__ b2,
    float* __restrict__ acc)
{
    const int tid = threadIdx.x;
    const int gi  = blockIdx.x * 256 + tid;
    if (gi < 2 * NQ) acc[gi] = 0.f;      // zero atomic accumulators

    const int row = blockIdx.x * 64 + (tid >> 2);
    const int p   = tid & 3;             // 8-elem chunk within the row
    if (row >= NQ + NB) return;

    const float* src; _Float16* dst; float* s2; float scale;
    if (row < NQ) { src = xq + (size_t)row * DIM;
                    dst = XQh + (size_t)row * DIM; s2 = q2 + row; scale = 1.f; }
    else          { int j = row - NQ;
                    src = xb + (size_t)j * DIM;
                    dst = XBh + (size_t)j * DIM;   s2 = b2 + j;   scale = -2.f; }

    const float4 xa  = ((const float4*)src)[p * 2];
    const float4 xbv = ((const float4*)src)[p * 2 + 1];
    const float4 wa  = ((const float4*)w)[p * 2];
    const float4 wb  = ((const float4*)w)[p * 2 + 1];
    const float xs[8]  = {xa.x, xa.y, xa.z, xa.w, xbv.x, xbv.y, xbv.z, xbv.w};
    const float ws_[8] = {wa.x, wa.y, wa.z, wa.w, wb.x, wb.y, wb.z, wb.w};

    half8 h;
    float s = 0.f;
#pragma unroll
    for (int c = 0; c < 8; ++c) {
        float t = xs[c] * ws_[c];
        _Float16 hh = (_Float16)t;       // the rounding
        float th = (float)hh;
        s = fmaf(th, th, s);             // norm of the ROUNDED vector
        h[c] = (_Float16)(th * scale);   // exact scaling
    }
    *(half8*)(dst + p * 8) = h;          // coalesced 16-B store

    // row-norm: reduce over the 4 chunk-lanes (low 2 lane bits)
    s += __shfl_xor(s, 1, 64);
    s += __shfl_xor(s, 2, 64);
    if (p == 0) *s2 = s;
}

// Main: grid (8, 128) = 1024 blocks (4/CU resident), 256 threads (4 waves).
// Block task: 16 queries x 1024 bg cols, in 4 col-quarters of 256.
//
// R12: R4 (512-B segs, 2 drains) ~= R5 (256-B segs, counted overlap) =>
// request granularity is the lever, overlap is secondary (16 waves/CU TLP
// already covers). Now BLOCK-cooperative staging: two 16-KB quarter
// buffers [16 rows][1 KB]; each gl_lds stages ONE FULL 1-KB CONTIGUOUS
// row-slice (4x R5's burst), 4 instr/wave/quarter. Wave wid computes cols
// qtr*256 + wid*64 + it*16. vmcnt ladder identical to R5 (vm4/vm12/vm4/
// vm0, per-wave counts verified against issue order below); raw s_barrier
// (no waitcnt drain) added around stage/compute since buffers are now
// cross-wave: each wave's counted vmcnt proves ITS loads landed, barrier
// orders across waves; barrier after compute makes overwrite safe.
// Swizzle: byte^=((rw&7)<<4) pre-applied on the GLOBAL source within each
// 1-KB slice (gl_lds dest linear lane*16 — both-sides-or-neither); read
// side XORs the same mask: LDS byte m*1024+Y holds global byte Y^swz(m),
// so reading Y=X^swz(m) returns global byte X (bijective). Max 2-way bank
// aliasing (free). aux (b2/yb) block-level 4 KB each, broadcast reads.
// Math identical to R3/R4/R5 -> absmax unchanged.
//
// R8 lesson (keep): __launch_bounds__(256,2) — (256,4) caps VGPR at 64 and
// spills everything. R5 lesson (keep): no __threadfence / fused finalize.
#define GLDS(GSRC, LDST)                                                    \
  __builtin_amdgcn_global_load_lds(                                         \
      (const __attribute__((address_space(1))) void*)(GSRC),                \
      (__attribute__((address_space(3))) void*)(LDST), 16, 0, 0)

#define SBAR __builtin_amdgcn_sched_barrier(0)
#define BARRIER __builtin_amdgcn_s_barrier()

// stage quarter QTR into BUF: wave wid stages rows wid*4..wid*4+3
#define STAGEQ(BUF, QTR)                                                    \
  { _Pragma("unroll") for (int j_ = 0; j_ < 4; ++j_)                        \
      GLDS(rq[j_] + (QTR) * 1024, (BUF) + (wid * 4 + j_) * 1024); }

// compute one quarter (4 MFMA tiles) out of block buffer BUF
#define COMPQ(BUF, QTR, AF)                                                 \
  { _Pragma("unroll") for (int it = 0; it < 4; ++it) {                      \
      const int co = (QTR) * 256 + wid * 64 + it * 16 + quad * 4;           \
      const f32x4 bb = *(const f32x4*)(b2l + co);                           \
      const f32x4 yv = *(const f32x4*)(ybl + co);                           \
      const f32x4 rr = *(const f32x4*)((BUF) + m * 1024 +                   \
          ((wid * 256 + it * 64 + quad * 16) ^ swz));                       \
      f32x4 cin;                                                            \
      _Pragma("unroll") for (int g = 0; g < 4; ++g) cin[g] = q2s + bb[g];   \
      const f32x4 d2v = __builtin_amdgcn_mfma_f32_16x16x32_f16(             \
          AF[it], qfrag, cin, 0, 0, 0);                                     \
      _Pragma("unroll") for (int g = 0; g < 4; ++g) {                       \
        float d2   = fmaxf(d2v[g], 0.f);                                    \
        float dist = __builtin_amdgcn_sqrtf(d2);                            \
        float e    = fmaf(dist, c1, rr[g] * c2);                            \
        float k    = __builtin_amdgcn_exp2f(e);                             \
        sk += k;                                                            \
        sky = fmaf(k, yv[g], sky); } } }

// A fragments for quarter Q (tile cols qtr*256 + wid*64 + I*16)
#define AFRAG(Q, I) (*(const half8*)(XBh +                                  \
    (size_t)(bcol0 + (Q) * 256 + wid * 64 + (I) * 16 + m) * DIM + quad * 8))

__global__ __launch_bounds__(256, 2) void relnw_main(
    const _Float16* __restrict__ XQh,  // (NQ, DIM)
    const _Float16* __restrict__ XBh,  // (NB, DIM), pre-scaled by -2
    const float* __restrict__ q2,      // (NQ,)
    const float* __restrict__ b2,      // (NB,)
    const float* __restrict__ yb,      // (NB,)
    const float* __restrict__ r,       // (NQ, NB)
    const float* __restrict__ sigma,   // (1,)
    const float* __restrict__ rscale,  // (1,)
    float* __restrict__ acc)           // [0:NQ]=sum_k, [NQ:2NQ]=sum_k*y
{
    // LDS: 2 x 16-KB r quarter buffers + 4-KB b2 + 4-KB yb (block-level)
    __shared__ char lds[2 * 16384 + 4096 + 4096];  // 40960 B

    const int tid  = threadIdx.x;
    const int lane = tid & 63;
    const int wid  = tid >> 6;
    const int m    = lane & 15;   // query col (D) / A-row feeder
    const int quad = lane >> 4;   // 0..3

    const int q0    = blockIdx.y * 16;
    const int bcol0 = blockIdx.x * 1024;   // block's 1024 bg cols

    char*  bufA = lds;
    char*  bufB = lds + 16384;
    float* b2l  = (float*)(lds + 32768);
    float* ybl  = (float*)(lds + 36864);

    const float c1 = -LOG2E / sigma[0];   // coeff on dist (log2 space)
    const float c2 =  LOG2E * rscale[0];  // coeff on r

    // B operand: this wave's 16 queries (fixed across the bg loop)
    const half8 qfrag = *(const half8*)(XQh + (size_t)(q0 + m) * DIM + quad * 8);
    const float q2s   = q2[q0 + m];
    const int   swz   = (m & 7) << 4;

    // r stage sources: wave wid stages rows rw = wid*4+j; each instruction
    // covers 1 KB CONTIGUOUS of row rw (lane*16, XOR-permuted in 128-B
    // windows by the pre-applied read swizzle).
    const char* rq[4];
#pragma unroll
    for (int j = 0; j < 4; ++j) {
        const int rw = wid * 4 + j;
        rq[j] = (const char*)(r + (size_t)(q0 + rw) * NB + bcol0)
                + ((lane * 16) ^ ((rw & 7) << 4));
    }

    half8 af0[4], af1[4], af2[4], af3[4];
    float sk = 0.f, sky = 0.f;

    // ---- prologue issue (per wave): af0,af1 (8) | aux (2) | Q0 (4) | Q1 (4)
#pragma unroll
    for (int i = 0; i < 4; ++i) af0[i] = AFRAG(0, i);
#pragma unroll
    for (int i = 0; i < 4; ++i) af1[i] = AFRAG(1, i);
    GLDS((const char*)(b2 + bcol0) + wid * 1024 + (lane & 63) * 16,
         (char*)b2l + wid * 1024);
    GLDS((const char*)(yb + bcol0) + wid * 1024 + (lane & 63) * 16,
         (char*)ybl + wid * 1024);
    STAGEQ(bufA, 0)
    STAGEQ(bufB, 1)
    SBAR;
    asm volatile("s_waitcnt vmcnt(4)" ::: "memory");  // all but Q1 done
    SBAR;
    BARRIER;                                          // Q0 staged block-wide

    COMPQ(bufA, 0, af0)
    BARRIER;                                          // bufA free to overwrite

    // ---- issue af2,af3 (8) | Q2->A (4); outstanding = Q1(4)+12 = 16 ----
#pragma unroll
    for (int i = 0; i < 4; ++i) af2[i] = AFRAG(2, i);
#pragma unroll
    for (int i = 0; i < 4; ++i) af3[i] = AFRAG(3, i);
    STAGEQ(bufA, 2)
    SBAR;
    asm volatile("s_waitcnt vmcnt(12)" ::: "memory"); // Q1 done
    SBAR;
    BARRIER;                                          // Q1 staged block-wide

    COMPQ(bufB, 1, af1)
    BARRIER;                                          // bufB free to overwrite

    // ---- issue Q3->B (4); outstanding = af2,af3(8)+Q2(4)+Q3(4) = 16 ----
    STAGEQ(bufB, 3)
    SBAR;
    asm volatile("s_waitcnt vmcnt(4)" ::: "memory");  // af2,af3,Q2 done
    SBAR;
    BARRIER;                                          // Q2 staged block-wide

    COMPQ(bufA, 2, af2)
    BARRIER;                                          // bufB... (A done)

    asm volatile("s_waitcnt vmcnt(0)" ::: "memory");  // Q3 done
    SBAR;
    BARRIER;                                          // Q3 staged block-wide

    COMPQ(bufB, 3, af3)

    // All 4 values of a lane belong to query q0+m; reduce across quads.
    sk  += __shfl_xor(sk, 16, 64);
    sk  += __shfl_xor(sk, 32, 64);
    sky += __shfl_xor(sky, 16, 64);
    sky += __shfl_xor(sky, 32, 64);
    if (lane < 16) {
        atomicAdd(acc + (q0 + m),      sk);
        atomicAdd(acc + NQ + (q0 + m), sky);
    }
}

__global__ __launch_bounds__(256) void relnw_finalize(
    const float* __restrict__ acc, float* __restrict__ out)
{
    int q = blockIdx.x * 256 + threadIdx.x;
    if (q < NQ)
        out[q] = acc[NQ + q] / (acc[q] + 1e-8f);
}

extern "C" void kernel_launch(void* const* d_in, const int* in_sizes, int n_in,
                              void* d_out, int out_size, void* d_ws, size_t ws_size,
                              hipStream_t stream) {
    const float* xb     = (const float*)d_in[0]; // (8192,32)
    const float* yb     = (const float*)d_in[1]; // (8192,)
    const float* xq     = (const float*)d_in[2]; // (2048,32)
    const float* r      = (const float*)d_in[3]; // (2048,8192)
    const float* sigma  = (const float*)d_in[4]; // (1,)
    const float* rscale = (const float*)d_in[5]; // (1,)
    const float* w      = (const float*)d_in[6]; // (32,)
    float* out = (float*)d_out;

    char* ws = (char*)d_ws;
    float*    acc = (float*)(ws + WS_ACC);
    float*    q2  = (float*)(ws + WS_Q2);
    float*    b2  = (float*)(ws + WS_B2);
    _Float16* XQh = (_Float16*)(ws + WS_XQH);
    _Float16* XBh = (_Float16*)(ws + WS_XBH);

    relnw_pre<<<(NQ + NB) / 64, 256, 0, stream>>>(xq, xb, w, XQh, XBh, q2, b2, acc);

    dim3 grid(NB / 1024, NQ / 16);  // (8, 128) = 1024 blocks
    relnw_main<<<grid, 256, 0, stream>>>(XQh, XBh, q2, b2, yb, r, sigma, rscale, acc);

    relnw_finalize<<<(NQ + 255) / 256, 256, 0, stream>>>(acc, out);
}